// Round 4
// baseline (10373.583 us; speedup 1.0000x reference)
//
#include <hip/hip_runtime.h>

#define B_ 16
#define N_ 4096
#define M_ 1024
#define S_ 32
#define IN_ 64
#define C0IN 67
#define NTOT (B_*M_*S_)
#define R2 0.04f
#define CAP 1024

// ---------------- FPS ----------------
// 512 threads (8 waves) per batch. 8 pts/lane in registers. One barrier/iter
// (double-buffered partials); every wave redundantly reduces the 8 partials
// so `cur` is uniform without a second barrier.
__global__ __launch_bounds__(512, 1) void fps_kernel(const float* __restrict__ xyz,
                                                     int* __restrict__ fps_idx,
                                                     float* __restrict__ out_xyz) {
#pragma clang fp contract(off)
    __shared__ float px[N_], py[N_], pz[N_];
    __shared__ float rv[2][8];
    __shared__ int   ri[2][8];
    int b = blockIdx.x, t = threadIdx.x;
    const float* xb = xyz + (size_t)b * N_ * 3;
    for (int i = t; i < N_; i += 512) {
        px[i] = xb[i*3+0]; py[i] = xb[i*3+1]; pz[i] = xb[i*3+2];
    }
    __syncthreads();
    float lx[8], ly[8], lz[8], dl[8];
#pragma unroll
    for (int j = 0; j < 8; j++) {
        int i = (j << 9) + t;
        lx[j] = px[i]; ly[j] = py[i]; lz[j] = pz[i];
        dl[j] = __builtin_inff();
    }
    int cur = 0;
    int wv = t >> 6;
    for (int k = 0; k < M_; k++) {
        float cx = px[cur], cy = py[cur], cz = pz[cur];
        if (t == 0) {
            fps_idx[b*M_ + k] = cur;
            out_xyz[(b*M_ + k)*3 + 0] = cx;
            out_xyz[(b*M_ + k)*3 + 1] = cy;
            out_xyz[(b*M_ + k)*3 + 2] = cz;
        }
        float bv = -1.0f; int bi = 0;
#pragma unroll
        for (int j = 0; j < 8; j++) {
            float dx = lx[j] - cx, dy = ly[j] - cy, dz = lz[j] - cz;
            float t0 = dx*dx, t1 = dy*dy, t2 = dz*dz;
            float d = (t0 + t1) + t2;
            float od = dl[j];
            float nd = d < od ? d : od;
            dl[j] = nd;
            if (nd > bv) { bv = nd; bi = (j << 9) + t; }  // strict > keeps first
        }
        for (int off = 32; off >= 1; off >>= 1) {
            float ov = __shfl_xor(bv, off, 64);
            int   oi = __shfl_xor(bi, off, 64);
            if (ov > bv || (ov == bv && oi < bi)) { bv = ov; bi = oi; }
        }
        int p = k & 1;
        if ((t & 63) == 0) { rv[p][wv] = bv; ri[p][wv] = bi; }
        __syncthreads();
        float v = rv[p][0]; int ix = ri[p][0];
#pragma unroll
        for (int j2 = 1; j2 < 8; j2++) {
            float v2 = rv[p][j2]; int i2 = ri[p][j2];
            if (v2 > v || (v2 == v && i2 < ix)) { v = v2; ix = i2; }
        }
        cur = ix;
    }
}

// ---------------- Ball query ---------------- (unchanged, fast)
__global__ __launch_bounds__(256) void ballq_kernel(const float* __restrict__ xyz,
                                                    const int* __restrict__ fps_idx,
                                                    int* __restrict__ ball_idx) {
#pragma clang fp contract(off)
    __shared__ float cd[CAP];
    __shared__ int   ci[CAP];
    __shared__ int   cnt;
    __shared__ float rv[4];
    __shared__ int   ri[4];
    __shared__ int   slots[33];
    int blk = blockIdx.x;
    int b = blk >> 10, m = blk & (M_ - 1);
    int t = threadIdx.x;
    if (t == 0) cnt = 0;
    __syncthreads();
    const float* xb = xyz + (size_t)b * N_ * 3;
    int cidx = fps_idx[b*M_ + m];
    float cx = xb[cidx*3+0], cy = xb[cidx*3+1], cz = xb[cidx*3+2];
    float bv = 3.4e38f; int bi = 0x7fffffff;
    for (int i = t; i < N_; i += 256) {
        float dx = xb[i*3+0] - cx, dy = xb[i*3+1] - cy, dz = xb[i*3+2] - cz;
        float t0 = dx*dx, t1 = dy*dy, t2 = dz*dz;
        float d = (t0 + t1) + t2;
        if (d < bv || (d == bv && i < bi)) { bv = d; bi = i; }
        if (d <= R2) {
            int p = atomicAdd(&cnt, 1);
            if (p < CAP) { cd[p] = d; ci[p] = i; }
        }
    }
    for (int off = 32; off >= 1; off >>= 1) {
        float ov = __shfl_xor(bv, off, 64);
        int   oi = __shfl_xor(bi, off, 64);
        if (ov < bv || (ov == bv && oi < bi)) { bv = ov; bi = oi; }
    }
    int w = t >> 6;
    if ((t & 63) == 0) { rv[w] = bv; ri[w] = bi; }
    __syncthreads();
    int n = cnt < CAP ? cnt : CAP;
    for (int j = t; j < n; j += 256) {
        float dj = cd[j]; int ij = ci[j];
        int rank = 0;
        for (int k = 0; k < n; k++) {
            float dk = cd[k]; int ik = ci[k];
            rank += (dk < dj) || (dk == dj && ik < ij);
        }
        if (rank < S_) slots[rank] = ij;
    }
    if (t == 0) {
        float v = rv[0]; int ix = ri[0];
        for (int j = 1; j < 4; j++)
            if (rv[j] < v || (rv[j] == v && ri[j] < ix)) { v = rv[j]; ix = ri[j]; }
        slots[32] = ix;
    }
    __syncthreads();
    if (t < S_) {
        int nearest = (n > 0) ? slots[0] : slots[32];
        int ix = (t < n) ? slots[t] : nearest;
        ball_idx[(size_t)(b*M_ + m)*S_ + t] = ix;
    }
}

// ================= MLP building blocks =================
// Thread map: s = t>>3 (32 rows), g = t&7 (8 col groups of 8). x-row in regs.
// LDS layouts (all conflict-free staging AND reads):
//   w64 : k-major, pitch 65  -> wT[k*65 + d];   stage lanes write consec dwords
//   w128: k-major, pitch 129 -> wT[k*129 + sidx], sidx = r*32 + g*4 + c
//         (d = g*16 + r*4 + c); reads k*129+r*32+g*4 hit all 32 banks exactly.

__device__ inline void stage_w64(const float* __restrict__ w, float* wT, int K, int t) {
    int tot = K * 64;
    for (int i = t; i < tot; i += 256) {
        int k = i >> 6, d = i & 63;
        wT[k*65 + d] = w[d*K + k];
    }
}
__device__ inline void stage_w128(const float* __restrict__ w, float* wT, int t) {
    for (int i = t; i < 8192; i += 256) {
        int k = i >> 7, j = i & 127;              // j = r*32 + g*4 + c
        int d = ((j >> 2) & 7) * 16 + (j >> 5) * 4 + (j & 3);
        wT[k*129 + j] = w[d*64 + k];
    }
}

template<int K>  // acc[j] <-> d = g*8+j, xs = row base (pitch 68)
__device__ inline void gemm64(const float* xs, const float* wT,
                              const float* __restrict__ bias, int g, float* acc) {
    constexpr int NLD = (K + 3) / 4;
    float xr[NLD*4];
#pragma unroll
    for (int i = 0; i < NLD; i++) *(float4*)&xr[i*4] = *(const float4*)&xs[i*4];
    float4 ba = *(const float4*)&bias[g*8], bb = *(const float4*)&bias[g*8+4];
    acc[0]=ba.x; acc[1]=ba.y; acc[2]=ba.z; acc[3]=ba.w;
    acc[4]=bb.x; acc[5]=bb.y; acc[6]=bb.z; acc[7]=bb.w;
#pragma unroll 8
    for (int k = 0; k < K; k++) {
        float4 wa = *(const float4*)&wT[k*65 + g*8];
        float4 wb = *(const float4*)&wT[k*65 + g*8 + 4];
        float x = xr[k];
        acc[0] += x*wa.x; acc[1] += x*wa.y; acc[2] += x*wa.z; acc[3] += x*wa.w;
        acc[4] += x*wb.x; acc[5] += x*wb.y; acc[6] += x*wb.z; acc[7] += x*wb.w;
    }
}

// acc[r*4+c] <-> d = g*16 + r*4 + c
__device__ inline void gemm128(const float* xs, const float* wT,
                               const float* __restrict__ bias, int g, float* acc) {
    float xr[64];
#pragma unroll
    for (int i = 0; i < 16; i++) *(float4*)&xr[i*4] = *(const float4*)&xs[i*4];
#pragma unroll
    for (int r = 0; r < 4; r++) {
        float4 bq = *(const float4*)&bias[g*16 + r*4];
        acc[r*4+0]=bq.x; acc[r*4+1]=bq.y; acc[r*4+2]=bq.z; acc[r*4+3]=bq.w;
    }
#pragma unroll 4
    for (int k = 0; k < 64; k++) {
        float x = xr[k];
#pragma unroll
        for (int r = 0; r < 4; r++) {
            float4 w = *(const float4*)&wT[k*129 + r*32 + g*4];
            acc[r*4+0] += x*w.x; acc[r*4+1] += x*w.y; acc[r*4+2] += x*w.z; acc[r*4+3] += x*w.w;
        }
    }
}

// shfl-reduce over s-in-wave (lane bits 3..5), LDS combine, global slice add.
template<int ND>
__device__ inline void stats_reduce(float* acc, int t, float* red, float* part) {
    constexpr int D = ND*8;
    int g = t & 7;
    float sq[ND];
#pragma unroll
    for (int j = 0; j < ND; j++) sq[j] = acc[j]*acc[j];
#pragma unroll
    for (int m = 8; m <= 32; m <<= 1) {
#pragma unroll
        for (int j = 0; j < ND; j++) {
            acc[j] += __shfl_xor(acc[j], m, 64);
            sq[j]  += __shfl_xor(sq[j], m, 64);
        }
    }
    if (((t >> 3) & 7) == 0) {
#pragma unroll
        for (int j = 0; j < ND; j++) {
            atomicAdd(&red[g*ND + j], acc[j]);
            atomicAdd(&red[D + g*ND + j], sq[j]);
        }
    }
    __syncthreads();
    for (int i = t; i < 2*D; i += 256) atomicAdd(&part[i], red[i]);
}

__device__ inline void bnrelu64(const float* acc, const float* __restrict__ ca,
                                const float* __restrict__ cc, int g, float* yrow) {
    float v[8];
#pragma unroll
    for (int j = 0; j < 8; j++) {
        int d = g*8 + j;
        float x = acc[j]*ca[d] + cc[d];
        v[j] = x > 0.f ? x : 0.f;
    }
    *(float4*)&yrow[g*8]   = make_float4(v[0],v[1],v[2],v[3]);
    *(float4*)&yrow[g*8+4] = make_float4(v[4],v[5],v[6],v[7]);
}

__device__ inline void gather_x(const float* __restrict__ xyz, const float* __restrict__ feat,
                                int b, float cx, float cy, float cz,
                                const int* idxs, float* xs, int t) {
    const float* xb = xyz + (size_t)b * N_ * 3;
    for (int i = t; i < S_*C0IN; i += 256) {
        int s = i / C0IN, c = i - s*C0IN;
        int p = idxs[s];
        float v;
        if (c == 0)      v = xb[p*3+0] - cx;
        else if (c == 1) v = xb[p*3+1] - cy;
        else if (c == 2) v = xb[p*3+2] - cz;
        else             v = feat[((size_t)b*N_ + p)*IN_ + (c - 3)];
        xs[s*68 + c] = v;
    }
}

// ---------------- MLP chain (4-pass recompute) ----------------
// One shared weight buffer (8256 fl), restaged per layer. y1 reuses xs.
// LDS ~= 52 KB -> 3 blocks/CU.
template<int MODE>
__global__ __launch_bounds__(256, 3) void mlp_kernel(
    const float* __restrict__ xyz, const float* __restrict__ feat,
    const int* __restrict__ fps_idx, const int* __restrict__ ball_idx,
    const float* __restrict__ w0, const float* __restrict__ b0,
    const float* __restrict__ w1, const float* __restrict__ b1,
    const float* __restrict__ w2, const float* __restrict__ b2,
    const float* __restrict__ coef, float* __restrict__ stats_part,
    float* __restrict__ out_feat) {
    __shared__ float wT[(MODE >= 2) ? 8256 : 4355];
    __shared__ float xs[2176];                       // x for L0; y1 for L2
    __shared__ float y0s[(MODE >= 1) ? 2176 : 4];
    __shared__ float red[(MODE >= 2) ? 256 : 128];
    __shared__ int idxs[32];
    constexpr int REDN = (MODE >= 2) ? 256 : 128;
    int t = threadIdx.x, blk = blockIdx.x;
    int b = blk >> 10;
    int s = t >> 3, g = t & 7;
    int slice = blk & 63;
    if (t < REDN) red[t] = 0.f;
    if (t < 32) idxs[t] = ball_idx[(size_t)blk*32 + t];
    __syncthreads();
    const float* xb = xyz + (size_t)b * N_ * 3;
    int cidx = fps_idx[blk];
    float cx = xb[cidx*3+0], cy = xb[cidx*3+1], cz = xb[cidx*3+2];
    gather_x(xyz, feat, b, cx, cy, cz, idxs, xs, t);
    stage_w64(w0, wT, 67, t);
    __syncthreads();
    float acc[8];
    gemm64<67>(xs + s*68, wT, b0, g, acc);
    if (MODE == 0) { stats_reduce<8>(acc, t, red, stats_part + slice*512); return; }
    bnrelu64(acc, coef, coef + 64, g, y0s + s*68);
    __syncthreads();
    stage_w64(w1, wT, 64, t);
    __syncthreads();
    gemm64<64>(y0s + s*68, wT, b1, g, acc);
    if (MODE == 1) { stats_reduce<8>(acc, t, red, stats_part + slice*512 + 128); return; }
    __syncthreads();                                  // xs reads done; reuse as y1
    bnrelu64(acc, coef + 128, coef + 192, g, xs + s*68);
    stage_w128(w2, wT, t);
    __syncthreads();
    float acc2[16];
    gemm128(xs + s*68, wT, b2, g, acc2);
    if (MODE == 2) { stats_reduce<16>(acc2, t, red, stats_part + slice*512 + 256); return; }
    // final: bn+relu+max over s
    const float* ca = coef + 256; const float* cc = coef + 384;
    int* redI = (int*)red;
#pragma unroll
    for (int j = 0; j < 16; j++) {
        int d = g*16 + ((j >> 2) * 4) + (j & 3);      // == g*16 + j
        float x = acc2[j]*ca[d] + cc[d];
        x = x > 0.f ? x : 0.f;
#pragma unroll
        for (int m = 8; m <= 32; m <<= 1) {
            float o = __shfl_xor(x, m, 64);
            x = o > x ? o : x;
        }
        acc2[j] = x;
    }
    if (((t >> 3) & 7) == 0) {
#pragma unroll
        for (int j = 0; j < 16; j++) atomicMax(&redI[g*16+j], __float_as_int(acc2[j]));
    }
    __syncthreads();
    if (t < 128) out_feat[(size_t)blk*128 + t] = __int_as_float(redI[t]);
}

// sum 64 slices -> mean/var -> affine coefs
__global__ void finalize_kernel(const float* __restrict__ part,
                                const float* __restrict__ gamma,
                                const float* __restrict__ beta,
                                float* __restrict__ coef, int C) {
    int t = threadIdx.x;
    if (t < C) {
        float sum = 0.f, sq = 0.f;
        for (int sl = 0; sl < 64; sl++) {
            sum += part[sl*512 + t];
            sq  += part[sl*512 + C + t];
        }
        float inv_n = 1.0f / (float)NTOT;
        float mean = sum * inv_n;
        float var = sq * inv_n - mean * mean;
        float rstd = 1.0f / sqrtf(var + 1e-5f);
        float a = gamma[t] * rstd;
        coef[t] = a;
        coef[C + t] = beta[t] - mean * a;
    }
}

extern "C" void kernel_launch(void* const* d_in, const int* in_sizes, int n_in,
                              void* d_out, int out_size, void* d_ws, size_t ws_size,
                              hipStream_t stream) {
    const float* xyz  = (const float*)d_in[0];
    const float* feat = (const float*)d_in[1];
    const float* w0 = (const float*)d_in[2];  const float* b0 = (const float*)d_in[3];
    const float* g0 = (const float*)d_in[4];  const float* be0 = (const float*)d_in[5];
    const float* w1 = (const float*)d_in[6];  const float* b1 = (const float*)d_in[7];
    const float* g1 = (const float*)d_in[8];  const float* be1 = (const float*)d_in[9];
    const float* w2 = (const float*)d_in[10]; const float* b2 = (const float*)d_in[11];
    const float* g2 = (const float*)d_in[12]; const float* be2 = (const float*)d_in[13];
    float* out_xyz  = (float*)d_out;
    float* out_feat = out_xyz + B_*M_*3;

    char* ws = (char*)d_ws;
    int* fps_i  = (int*)ws;                                  // 65536 B
    int* ball_i = (int*)(ws + 65536);                        // 2097152 B
    float* stats_part = (float*)(ws + 65536 + 2097152);      // 64*512*4 = 131072 B
    float* coef = (float*)(ws + 65536 + 2097152 + 131072);   // 2048 B

    hipMemsetAsync(stats_part, 0, 131072, stream);
    fps_kernel<<<B_, 512, 0, stream>>>(xyz, fps_i, out_xyz);
    ballq_kernel<<<B_*M_, 256, 0, stream>>>(xyz, fps_i, ball_i);
    mlp_kernel<0><<<B_*M_, 256, 0, stream>>>(xyz, feat, fps_i, ball_i,
        w0, b0, w1, b1, w2, b2, coef, stats_part, out_feat);
    finalize_kernel<<<1, 64, 0, stream>>>(stats_part, g0, be0, coef, 64);
    mlp_kernel<1><<<B_*M_, 256, 0, stream>>>(xyz, feat, fps_i, ball_i,
        w0, b0, w1, b1, w2, b2, coef, stats_part, out_feat);
    finalize_kernel<<<1, 64, 0, stream>>>(stats_part + 128, g1, be1, coef + 128, 64);
    mlp_kernel<2><<<B_*M_, 256, 0, stream>>>(xyz, feat, fps_i, ball_i,
        w0, b0, w1, b1, w2, b2, coef, stats_part, out_feat);
    finalize_kernel<<<1, 128, 0, stream>>>(stats_part + 256, g2, be2, coef + 256, 128);
    mlp_kernel<3><<<B_*M_, 256, 0, stream>>>(xyz, feat, fps_i, ball_i,
        w0, b0, w1, b1, w2, b2, coef, stats_part, out_feat);
}

// Round 5
// 7348.486 us; speedup vs baseline: 1.4117x; 1.4117x over previous
//
#include <hip/hip_runtime.h>

#define B_ 16
#define N_ 4096
#define M_ 1024
#define S_ 32
#define IN_ 64
#define C0IN 67
#define NTOT (B_*M_*S_)
#define R2 0.04f
#define CAP 1024

// ---------------- FPS ----------------
__global__ __launch_bounds__(512, 1) void fps_kernel(const float* __restrict__ xyz,
                                                     int* __restrict__ fps_idx,
                                                     float* __restrict__ out_xyz) {
#pragma clang fp contract(off)
    __shared__ float px[N_], py[N_], pz[N_];
    __shared__ float rv[2][8];
    __shared__ int   ri[2][8];
    int b = blockIdx.x, t = threadIdx.x;
    const float* xb = xyz + (size_t)b * N_ * 3;
    for (int i = t; i < N_; i += 512) {
        px[i] = xb[i*3+0]; py[i] = xb[i*3+1]; pz[i] = xb[i*3+2];
    }
    __syncthreads();
    float lx[8], ly[8], lz[8], dl[8];
#pragma unroll
    for (int j = 0; j < 8; j++) {
        int i = (j << 9) + t;
        lx[j] = px[i]; ly[j] = py[i]; lz[j] = pz[i];
        dl[j] = __builtin_inff();
    }
    int cur = 0;
    int wv = t >> 6;
    for (int k = 0; k < M_; k++) {
        float cx = px[cur], cy = py[cur], cz = pz[cur];
        if (t == 0) {
            fps_idx[b*M_ + k] = cur;
            out_xyz[(b*M_ + k)*3 + 0] = cx;
            out_xyz[(b*M_ + k)*3 + 1] = cy;
            out_xyz[(b*M_ + k)*3 + 2] = cz;
        }
        float bv = -1.0f; int bi = 0;
#pragma unroll
        for (int j = 0; j < 8; j++) {
            float dx = lx[j] - cx, dy = ly[j] - cy, dz = lz[j] - cz;
            float t0 = dx*dx, t1 = dy*dy, t2 = dz*dz;
            float d = (t0 + t1) + t2;
            float od = dl[j];
            float nd = d < od ? d : od;
            dl[j] = nd;
            if (nd > bv) { bv = nd; bi = (j << 9) + t; }
        }
        for (int off = 32; off >= 1; off >>= 1) {
            float ov = __shfl_xor(bv, off, 64);
            int   oi = __shfl_xor(bi, off, 64);
            if (ov > bv || (ov == bv && oi < bi)) { bv = ov; bi = oi; }
        }
        int p = k & 1;
        if ((t & 63) == 0) { rv[p][wv] = bv; ri[p][wv] = bi; }
        __syncthreads();
        float v = rv[p][0]; int ix = ri[p][0];
#pragma unroll
        for (int j2 = 1; j2 < 8; j2++) {
            float v2 = rv[p][j2]; int i2 = ri[p][j2];
            if (v2 > v || (v2 == v && i2 < ix)) { v = v2; ix = i2; }
        }
        cur = ix;
    }
}

// ---------------- Ball query ----------------
__global__ __launch_bounds__(256) void ballq_kernel(const float* __restrict__ xyz,
                                                    const int* __restrict__ fps_idx,
                                                    int* __restrict__ ball_idx) {
#pragma clang fp contract(off)
    __shared__ float cd[CAP];
    __shared__ int   ci[CAP];
    __shared__ int   cnt;
    __shared__ float rv[4];
    __shared__ int   ri[4];
    __shared__ int   slots[33];
    int blk = blockIdx.x;
    int b = blk >> 10, m = blk & (M_ - 1);
    int t = threadIdx.x;
    if (t == 0) cnt = 0;
    __syncthreads();
    const float* xb = xyz + (size_t)b * N_ * 3;
    int cidx = fps_idx[b*M_ + m];
    float cx = xb[cidx*3+0], cy = xb[cidx*3+1], cz = xb[cidx*3+2];
    float bv = 3.4e38f; int bi = 0x7fffffff;
    for (int i = t; i < N_; i += 256) {
        float dx = xb[i*3+0] - cx, dy = xb[i*3+1] - cy, dz = xb[i*3+2] - cz;
        float t0 = dx*dx, t1 = dy*dy, t2 = dz*dz;
        float d = (t0 + t1) + t2;
        if (d < bv || (d == bv && i < bi)) { bv = d; bi = i; }
        if (d <= R2) {
            int p = atomicAdd(&cnt, 1);
            if (p < CAP) { cd[p] = d; ci[p] = i; }
        }
    }
    for (int off = 32; off >= 1; off >>= 1) {
        float ov = __shfl_xor(bv, off, 64);
        int   oi = __shfl_xor(bi, off, 64);
        if (ov < bv || (ov == bv && oi < bi)) { bv = ov; bi = oi; }
    }
    int w = t >> 6;
    if ((t & 63) == 0) { rv[w] = bv; ri[w] = bi; }
    __syncthreads();
    int n = cnt < CAP ? cnt : CAP;
    for (int j = t; j < n; j += 256) {
        float dj = cd[j]; int ij = ci[j];
        int rank = 0;
        for (int k = 0; k < n; k++) {
            float dk = cd[k]; int ik = ci[k];
            rank += (dk < dj) || (dk == dj && ik < ij);
        }
        if (rank < S_) slots[rank] = ij;
    }
    if (t == 0) {
        float v = rv[0]; int ix = ri[0];
        for (int j = 1; j < 4; j++)
            if (rv[j] < v || (rv[j] == v && ri[j] < ix)) { v = rv[j]; ix = ri[j]; }
        slots[32] = ix;
    }
    __syncthreads();
    if (t < S_) {
        int nearest = (n > 0) ? slots[0] : slots[32];
        int ix = (t < n) ? slots[t] : nearest;
        ball_idx[(size_t)(b*M_ + m)*S_ + t] = ix;
    }
}

// ================= MLP building blocks =================
// LDS pitches 65/129 (both = 1 mod 32): staging with consecutive-lane k
// (coalesced global reads) writes bank (k+d)%32 -> conflict-free. Reads as
// in R4 (conflict-free).

__device__ inline unsigned bfpack(float a, float b) {
    unsigned ua = __float_as_uint(a); ua = (ua + 0x7fffu + ((ua >> 16) & 1u)) >> 16;
    unsigned ub = __float_as_uint(b); ub = (ub + 0x7fffu + ((ub >> 16) & 1u)) >> 16;
    return ua | (ub << 16);
}
__device__ inline float bflo(unsigned u) { return __uint_as_float(u << 16); }
__device__ inline float bfhi(unsigned u) { return __uint_as_float(u & 0xffff0000u); }

template<int K>   // w: [64][K] row-major -> wT[k*65 + d]
__device__ inline void stage_w64(const float* __restrict__ w, float* wT, int t) {
    constexpr int tot = K * 64;
    for (int i = t; i < tot; i += 256) {
        int d = i / K, k = i - d * K;          // consecutive i -> coalesced global
        wT[k*65 + d] = w[i];
    }
}
// w2: [128][64] -> wT[k*129 + sidx], sidx = r*32+g*4+c for d = g*16+r*4+c
__device__ inline void stage_w128(const float* __restrict__ w, float* wT, int t) {
    for (int i = t; i < 8192; i += 256) {
        int d = i >> 6, k = i & 63;            // consecutive i -> coalesced global
        int sidx = ((d >> 2) & 3) * 32 + (d >> 4) * 4 + (d & 3);
        wT[k*129 + sidx] = w[i];
    }
}

template<int K>  // acc[j] <-> d = g*8+j, xs = row base (pitch 68)
__device__ inline void gemm64(const float* xs, const float* wT,
                              const float* __restrict__ bias, int g, float* acc) {
    constexpr int NLD = (K + 3) / 4;
    float xr[NLD*4];
#pragma unroll
    for (int i = 0; i < NLD; i++) *(float4*)&xr[i*4] = *(const float4*)&xs[i*4];
    float4 ba = *(const float4*)&bias[g*8], bb = *(const float4*)&bias[g*8+4];
    acc[0]=ba.x; acc[1]=ba.y; acc[2]=ba.z; acc[3]=ba.w;
    acc[4]=bb.x; acc[5]=bb.y; acc[6]=bb.z; acc[7]=bb.w;
#pragma unroll 8
    for (int k = 0; k < K; k++) {
        float4 wa = *(const float4*)&wT[k*65 + g*8];
        float4 wb = *(const float4*)&wT[k*65 + g*8 + 4];
        float x = xr[k];
        acc[0] += x*wa.x; acc[1] += x*wa.y; acc[2] += x*wa.z; acc[3] += x*wa.w;
        acc[4] += x*wb.x; acc[5] += x*wb.y; acc[6] += x*wb.z; acc[7] += x*wb.w;
    }
}

// acc[r*4+c] <-> d = g*16 + r*4 + c
__device__ inline void gemm128_core(const float* xr, const float* wT,
                                    const float* __restrict__ bias, int g, float* acc) {
#pragma unroll
    for (int r = 0; r < 4; r++) {
        float4 bq = *(const float4*)&bias[g*16 + r*4];
        acc[r*4+0]=bq.x; acc[r*4+1]=bq.y; acc[r*4+2]=bq.z; acc[r*4+3]=bq.w;
    }
#pragma unroll 4
    for (int k = 0; k < 64; k++) {
        float x = xr[k];
#pragma unroll
        for (int r = 0; r < 4; r++) {
            float4 w = *(const float4*)&wT[k*129 + r*32 + g*4];
            acc[r*4+0] += x*w.x; acc[r*4+1] += x*w.y; acc[r*4+2] += x*w.z; acc[r*4+3] += x*w.w;
        }
    }
}

template<int ND>
__device__ inline void stats_reduce(float* acc, int t, float* red, float* part) {
    constexpr int D = ND*8;
    int g = t & 7;
    float sq[ND];
#pragma unroll
    for (int j = 0; j < ND; j++) sq[j] = acc[j]*acc[j];
#pragma unroll
    for (int m = 8; m <= 32; m <<= 1) {
#pragma unroll
        for (int j = 0; j < ND; j++) {
            acc[j] += __shfl_xor(acc[j], m, 64);
            sq[j]  += __shfl_xor(sq[j], m, 64);
        }
    }
    if (((t >> 3) & 7) == 0) {
#pragma unroll
        for (int j = 0; j < ND; j++) {
            atomicAdd(&red[g*ND + j], acc[j]);
            atomicAdd(&red[D + g*ND + j], sq[j]);
        }
    }
    __syncthreads();
    for (int i = t; i < 2*D; i += 256) atomicAdd(&part[i], red[i]);
}

// bn+relu into LDS row; optionally pack bf16 to global cache (y1 cache)
template<bool WC>
__device__ inline void bnrelu64(const float* acc, const float* __restrict__ ca,
                                const float* __restrict__ cc, int g, float* yrow,
                                unsigned short* ycg) {
    float v[8];
#pragma unroll
    for (int j = 0; j < 8; j++) {
        int d = g*8 + j;
        float x = acc[j]*ca[d] + cc[d];
        v[j] = x > 0.f ? x : 0.f;
    }
    *(float4*)&yrow[g*8]   = make_float4(v[0],v[1],v[2],v[3]);
    *(float4*)&yrow[g*8+4] = make_float4(v[4],v[5],v[6],v[7]);
    if (WC) {
        uint4 q;
        q.x = bfpack(v[0],v[1]); q.y = bfpack(v[2],v[3]);
        q.z = bfpack(v[4],v[5]); q.w = bfpack(v[6],v[7]);
        *(uint4*)(ycg + g*8) = q;   // ycg = y1c + blk*2048 + s*64
    }
}

__device__ inline void gather_x(const float* __restrict__ xyz, const float* __restrict__ feat,
                                int b, float cx, float cy, float cz,
                                const int* idxs, float* xs, int t) {
    const float* xb = xyz + (size_t)b * N_ * 3;
    for (int i = t; i < S_*C0IN; i += 256) {
        int s = i / C0IN, c = i - s*C0IN;
        int p = idxs[s];
        float v;
        if (c == 0)      v = xb[p*3+0] - cx;
        else if (c == 1) v = xb[p*3+1] - cy;
        else if (c == 2) v = xb[p*3+2] - cz;
        else             v = feat[((size_t)b*N_ + p)*IN_ + (c - 3)];
        xs[s*68 + c] = v;
    }
}

// ---------------- MLP chain ----------------
// MODE: 0..3 as before. CACHE (ws-gated): mode2: 1=write y1-bf16, 2=write
// z2-bf16; mode3: 1=read y1-bf16 (skip L0/L1). 0 = pure recompute.
template<int MODE, int CACHE>
__global__ __launch_bounds__(256, 3) void mlp_kernel(
    const float* __restrict__ xyz, const float* __restrict__ feat,
    const int* __restrict__ fps_idx, const int* __restrict__ ball_idx,
    const float* __restrict__ w0, const float* __restrict__ b0,
    const float* __restrict__ w1, const float* __restrict__ b1,
    const float* __restrict__ w2, const float* __restrict__ b2,
    const float* __restrict__ coef, float* __restrict__ stats_part,
    unsigned short* __restrict__ zc, float* __restrict__ out_feat) {
    constexpr bool SKIP01 = (MODE == 3 && CACHE == 1);
    __shared__ float wT[(MODE >= 2) ? 8256 : 4355];
    __shared__ float xs[SKIP01 ? 4 : 2176];
    __shared__ float y0s[(MODE >= 1 && !SKIP01) ? 2176 : 4];
    __shared__ float red[(MODE >= 2) ? 256 : 128];
    __shared__ int idxs[32];
    constexpr int REDN = (MODE >= 2) ? 256 : 128;
    int t = threadIdx.x, blk = blockIdx.x;
    int b = blk >> 10;
    int s = t >> 3, g = t & 7;
    int slice = blk & 63;
    if (t < REDN) red[t] = 0.f;

    float xr2[SKIP01 ? 64 : 4];
    if (SKIP01) {
        stage_w128(w2, wT, t);
        const uint4* yr = (const uint4*)(zc + (size_t)blk*2048 + s*64);
#pragma unroll
        for (int i = 0; i < 8; i++) {
            uint4 q = yr[i];
            xr2[i*8+0]=bflo(q.x); xr2[i*8+1]=bfhi(q.x);
            xr2[i*8+2]=bflo(q.y); xr2[i*8+3]=bfhi(q.y);
            xr2[i*8+4]=bflo(q.z); xr2[i*8+5]=bfhi(q.z);
            xr2[i*8+6]=bflo(q.w); xr2[i*8+7]=bfhi(q.w);
        }
        __syncthreads();
    } else {
        if (t < 32) idxs[t] = ball_idx[(size_t)blk*32 + t];
        __syncthreads();
        const float* xb = xyz + (size_t)b * N_ * 3;
        int cidx = fps_idx[blk];
        float cx = xb[cidx*3+0], cy = xb[cidx*3+1], cz = xb[cidx*3+2];
        gather_x(xyz, feat, b, cx, cy, cz, idxs, xs, t);
        stage_w64<67>(w0, wT, t);
        __syncthreads();
    }

    if (!SKIP01) {
        float acc[8];
        gemm64<67>(xs + s*68, wT, b0, g, acc);
        if (MODE == 0) { stats_reduce<8>(acc, t, red, stats_part + slice*512); return; }
        bnrelu64<false>(acc, coef, coef + 64, g, y0s + s*68, nullptr);
        __syncthreads();
        stage_w64<64>(w1, wT, t);
        __syncthreads();
        gemm64<64>(y0s + s*68, wT, b1, g, acc);
        if (MODE == 1) { stats_reduce<8>(acc, t, red, stats_part + slice*512 + 128); return; }
        __syncthreads();                                  // xs reads done; reuse as y1
        bnrelu64<(MODE == 2 && CACHE == 1)>(acc, coef + 128, coef + 192, g, xs + s*68,
                                            zc + (size_t)blk*2048 + s*64);
        stage_w128(w2, wT, t);
        __syncthreads();
#pragma unroll
        for (int i = 0; i < 16; i++)
            *(float4*)&xr2[0] == *(float4*)&xr2[0];       // no-op to keep xr2 alive path-safe
    }

    float acc2[16];
    if (SKIP01) {
        gemm128_core(xr2, wT, b2, g, acc2);
    } else {
        float xr[64];
#pragma unroll
        for (int i = 0; i < 16; i++) *(float4*)&xr[i*4] = *(const float4*)&xs[s*68 + i*4];
        gemm128_core(xr, wT, b2, g, acc2);
    }
    if (MODE == 2 && CACHE == 2) {
        unsigned short* zw = zc + (size_t)blk*4096 + s*128 + g*16;
        uint4 qa, qb;
        qa.x = bfpack(acc2[0],acc2[1]);   qa.y = bfpack(acc2[2],acc2[3]);
        qa.z = bfpack(acc2[4],acc2[5]);   qa.w = bfpack(acc2[6],acc2[7]);
        qb.x = bfpack(acc2[8],acc2[9]);   qb.y = bfpack(acc2[10],acc2[11]);
        qb.z = bfpack(acc2[12],acc2[13]); qb.w = bfpack(acc2[14],acc2[15]);
        *(uint4*)zw = qa; *(uint4*)(zw + 8) = qb;
    }
    if (MODE == 2) { stats_reduce<16>(acc2, t, red, stats_part + slice*512 + 256); return; }
    // final: bn+relu+max over s
    const float* ca = coef + 256; const float* cc = coef + 384;
    int* redI = (int*)red;
#pragma unroll
    for (int j = 0; j < 16; j++) {
        int d = g*16 + j;
        float x = acc2[j]*ca[d] + cc[d];
        x = x > 0.f ? x : 0.f;
#pragma unroll
        for (int m = 8; m <= 32; m <<= 1) {
            float o = __shfl_xor(x, m, 64);
            x = o > x ? o : x;
        }
        acc2[j] = x;
    }
    if (((t >> 3) & 7) == 0) {
#pragma unroll
        for (int j = 0; j < 16; j++) atomicMax(&redI[g*16+j], __float_as_int(acc2[j]));
    }
    __syncthreads();
    if (t < 128) out_feat[(size_t)blk*128 + t] = __int_as_float(redI[t]);
}

// gate-A finisher: read z2-bf16, bn+relu+max
__global__ __launch_bounds__(256) void f3_kernel(const unsigned short* __restrict__ zc,
                                                 const float* __restrict__ coef,
                                                 float* __restrict__ out_feat) {
    __shared__ int red[128];
    int t = threadIdx.x, blk = blockIdx.x;
    int g = t & 7;
    if (t < 128) red[t] = 0;   // outputs are post-ReLU >= 0
    __syncthreads();
    const uint4* zr = (const uint4*)(zc + (size_t)blk*4096 + t*16);
    uint4 q0 = zr[0], q1 = zr[1];
    float v[16];
    v[0]=bflo(q0.x); v[1]=bfhi(q0.x); v[2]=bflo(q0.y); v[3]=bfhi(q0.y);
    v[4]=bflo(q0.z); v[5]=bfhi(q0.z); v[6]=bflo(q0.w); v[7]=bfhi(q0.w);
    v[8]=bflo(q1.x); v[9]=bfhi(q1.x); v[10]=bflo(q1.y); v[11]=bfhi(q1.y);
    v[12]=bflo(q1.z); v[13]=bfhi(q1.z); v[14]=bflo(q1.w); v[15]=bfhi(q1.w);
    const float* ca = coef; const float* cc = coef + 128;
#pragma unroll
    for (int j = 0; j < 16; j++) {
        int d = g*16 + j;
        float x = v[j]*ca[d] + cc[d];
        x = x > 0.f ? x : 0.f;
#pragma unroll
        for (int m = 8; m <= 32; m <<= 1) {
            float o = __shfl_xor(x, m, 64);
            x = o > x ? o : x;
        }
        if (((t >> 3) & 7) == 0) atomicMax(&red[d], __float_as_int(x));
    }
    __syncthreads();
    if (t < 128) out_feat[(size_t)blk*128 + t] = __int_as_float(red[t]);
}

__global__ void finalize_kernel(const float* __restrict__ part,
                                const float* __restrict__ gamma,
                                const float* __restrict__ beta,
                                float* __restrict__ coef, int C) {
    int t = threadIdx.x;
    if (t < C) {
        float sum = 0.f, sq = 0.f;
        for (int sl = 0; sl < 64; sl++) {
            sum += part[sl*512 + t];
            sq  += part[sl*512 + C + t];
        }
        float inv_n = 1.0f / (float)NTOT;
        float mean = sum * inv_n;
        float var = sq * inv_n - mean * mean;
        float rstd = 1.0f / sqrtf(var + 1e-5f);
        float a = gamma[t] * rstd;
        coef[t] = a;
        coef[C + t] = beta[t] - mean * a;
    }
}

extern "C" void kernel_launch(void* const* d_in, const int* in_sizes, int n_in,
                              void* d_out, int out_size, void* d_ws, size_t ws_size,
                              hipStream_t stream) {
    const float* xyz  = (const float*)d_in[0];
    const float* feat = (const float*)d_in[1];
    const float* w0 = (const float*)d_in[2];  const float* b0 = (const float*)d_in[3];
    const float* g0 = (const float*)d_in[4];  const float* be0 = (const float*)d_in[5];
    const float* w1 = (const float*)d_in[6];  const float* b1 = (const float*)d_in[7];
    const float* g1 = (const float*)d_in[8];  const float* be1 = (const float*)d_in[9];
    const float* w2 = (const float*)d_in[10]; const float* b2 = (const float*)d_in[11];
    const float* g2 = (const float*)d_in[12]; const float* be2 = (const float*)d_in[13];
    float* out_xyz  = (float*)d_out;
    float* out_feat = out_xyz + B_*M_*3;

    char* ws = (char*)d_ws;
    int* fps_i  = (int*)ws;                                  // 65536 B
    int* ball_i = (int*)(ws + 65536);                        // 2097152 B
    float* stats_part = (float*)(ws + 65536 + 2097152);      // 131072 B
    float* coef = (float*)(ws + 65536 + 2097152 + 131072);   // 2048 B
    unsigned short* zc = (unsigned short*)(ws + ((size_t)4 << 20));
    bool gateA = ws_size >= ((size_t)4 << 20) + 134217728ull + (1u << 20);  // z2-bf16
    bool gateB = !gateA && ws_size >= ((size_t)4 << 20) + 67108864ull + (1u << 20); // y1-bf16

    hipMemsetAsync(stats_part, 0, 131072, stream);
    fps_kernel<<<B_, 512, 0, stream>>>(xyz, fps_i, out_xyz);
    ballq_kernel<<<B_*M_, 256, 0, stream>>>(xyz, fps_i, ball_i);
    mlp_kernel<0,0><<<B_*M_, 256, 0, stream>>>(xyz, feat, fps_i, ball_i,
        w0, b0, w1, b1, w2, b2, coef, stats_part, zc, out_feat);
    finalize_kernel<<<1, 64, 0, stream>>>(stats_part, g0, be0, coef, 64);
    mlp_kernel<1,0><<<B_*M_, 256, 0, stream>>>(xyz, feat, fps_i, ball_i,
        w0, b0, w1, b1, w2, b2, coef, stats_part, zc, out_feat);
    finalize_kernel<<<1, 64, 0, stream>>>(stats_part + 128, g1, be1, coef + 128, 64);
    if (gateA)
        mlp_kernel<2,2><<<B_*M_, 256, 0, stream>>>(xyz, feat, fps_i, ball_i,
            w0, b0, w1, b1, w2, b2, coef, stats_part, zc, out_feat);
    else if (gateB)
        mlp_kernel<2,1><<<B_*M_, 256, 0, stream>>>(xyz, feat, fps_i, ball_i,
            w0, b0, w1, b1, w2, b2, coef, stats_part, zc, out_feat);
    else
        mlp_kernel<2,0><<<B_*M_, 256, 0, stream>>>(xyz, feat, fps_i, ball_i,
            w0, b0, w1, b1, w2, b2, coef, stats_part, zc, out_feat);
    finalize_kernel<<<1, 128, 0, stream>>>(stats_part + 256, g2, be2, coef + 256, 128);
    if (gateA)
        f3_kernel<<<B_*M_, 256, 0, stream>>>(zc, coef + 256, out_feat);
    else if (gateB)
        mlp_kernel<3,1><<<B_*M_, 256, 0, stream>>>(xyz, feat, fps_i, ball_i,
            w0, b0, w1, b1, w2, b2, coef, stats_part, zc, out_feat);
    else
        mlp_kernel<3,0><<<B_*M_, 256, 0, stream>>>(xyz, feat, fps_i, ball_i,
            w0, b0, w1, b1, w2, b2, coef, stats_part, zc, out_feat);
}

// Round 6
// 7035.834 us; speedup vs baseline: 1.4744x; 1.0444x over previous
//
#include <hip/hip_runtime.h>

#define B_ 16
#define N_ 4096
#define M_ 1024
#define S_ 32
#define IN_ 64
#define C0IN 67
#define NTOT (B_*M_*S_)
#define R2 0.04f
#define CAP 1024

// ---------------- FPS ----------------
__global__ __launch_bounds__(512, 1) void fps_kernel(const float* __restrict__ xyz,
                                                     int* __restrict__ fps_idx,
                                                     float* __restrict__ out_xyz) {
#pragma clang fp contract(off)
    __shared__ float px[N_], py[N_], pz[N_];
    __shared__ float rv[2][8];
    __shared__ int   ri[2][8];
    int b = blockIdx.x, t = threadIdx.x;
    const float* xb = xyz + (size_t)b * N_ * 3;
    for (int i = t; i < N_; i += 512) {
        px[i] = xb[i*3+0]; py[i] = xb[i*3+1]; pz[i] = xb[i*3+2];
    }
    __syncthreads();
    float lx[8], ly[8], lz[8], dl[8];
#pragma unroll
    for (int j = 0; j < 8; j++) {
        int i = (j << 9) + t;
        lx[j] = px[i]; ly[j] = py[i]; lz[j] = pz[i];
        dl[j] = __builtin_inff();
    }
    int cur = 0;
    int wv = t >> 6;
    for (int k = 0; k < M_; k++) {
        float cx = px[cur], cy = py[cur], cz = pz[cur];
        if (t == 0) {
            fps_idx[b*M_ + k] = cur;
            out_xyz[(b*M_ + k)*3 + 0] = cx;
            out_xyz[(b*M_ + k)*3 + 1] = cy;
            out_xyz[(b*M_ + k)*3 + 2] = cz;
        }
        float bv = -1.0f; int bi = 0;
#pragma unroll
        for (int j = 0; j < 8; j++) {
            float dx = lx[j] - cx, dy = ly[j] - cy, dz = lz[j] - cz;
            float t0 = dx*dx, t1 = dy*dy, t2 = dz*dz;
            float d = (t0 + t1) + t2;
            float od = dl[j];
            float nd = d < od ? d : od;
            dl[j] = nd;
            if (nd > bv) { bv = nd; bi = (j << 9) + t; }
        }
        for (int off = 32; off >= 1; off >>= 1) {
            float ov = __shfl_xor(bv, off, 64);
            int   oi = __shfl_xor(bi, off, 64);
            if (ov > bv || (ov == bv && oi < bi)) { bv = ov; bi = oi; }
        }
        int p = k & 1;
        if ((t & 63) == 0) { rv[p][wv] = bv; ri[p][wv] = bi; }
        __syncthreads();
        float v = rv[p][0]; int ix = ri[p][0];
#pragma unroll
        for (int j2 = 1; j2 < 8; j2++) {
            float v2 = rv[p][j2]; int i2 = ri[p][j2];
            if (v2 > v || (v2 == v && i2 < ix)) { v = v2; ix = i2; }
        }
        cur = ix;
    }
}

// ---------------- Ball query ----------------
__global__ __launch_bounds__(256) void ballq_kernel(const float* __restrict__ xyz,
                                                    const int* __restrict__ fps_idx,
                                                    int* __restrict__ ball_idx) {
#pragma clang fp contract(off)
    __shared__ float cd[CAP];
    __shared__ int   ci[CAP];
    __shared__ int   cnt;
    __shared__ float rv[4];
    __shared__ int   ri[4];
    __shared__ int   slots[33];
    int blk = blockIdx.x;
    int b = blk >> 10, m = blk & (M_ - 1);
    int t = threadIdx.x;
    if (t == 0) cnt = 0;
    __syncthreads();
    const float* xb = xyz + (size_t)b * N_ * 3;
    int cidx = fps_idx[b*M_ + m];
    float cx = xb[cidx*3+0], cy = xb[cidx*3+1], cz = xb[cidx*3+2];
    float bv = 3.4e38f; int bi = 0x7fffffff;
    for (int i = t; i < N_; i += 256) {
        float dx = xb[i*3+0] - cx, dy = xb[i*3+1] - cy, dz = xb[i*3+2] - cz;
        float t0 = dx*dx, t1 = dy*dy, t2 = dz*dz;
        float d = (t0 + t1) + t2;
        if (d < bv || (d == bv && i < bi)) { bv = d; bi = i; }
        if (d <= R2) {
            int p = atomicAdd(&cnt, 1);
            if (p < CAP) { cd[p] = d; ci[p] = i; }
        }
    }
    for (int off = 32; off >= 1; off >>= 1) {
        float ov = __shfl_xor(bv, off, 64);
        int   oi = __shfl_xor(bi, off, 64);
        if (ov < bv || (ov == bv && oi < bi)) { bv = ov; bi = oi; }
    }
    int w = t >> 6;
    if ((t & 63) == 0) { rv[w] = bv; ri[w] = bi; }
    __syncthreads();
    int n = cnt < CAP ? cnt : CAP;
    for (int j = t; j < n; j += 256) {
        float dj = cd[j]; int ij = ci[j];
        int rank = 0;
        for (int k = 0; k < n; k++) {
            float dk = cd[k]; int ik = ci[k];
            rank += (dk < dj) || (dk == dj && ik < ij);
        }
        if (rank < S_) slots[rank] = ij;
    }
    if (t == 0) {
        float v = rv[0]; int ix = ri[0];
        for (int j = 1; j < 4; j++)
            if (rv[j] < v || (rv[j] == v && ri[j] < ix)) { v = rv[j]; ix = ri[j]; }
        slots[32] = ix;
    }
    __syncthreads();
    if (t < S_) {
        int nearest = (n > 0) ? slots[0] : slots[32];
        int ix = (t < n) ? slots[t] : nearest;
        ball_idx[(size_t)(b*M_ + m)*S_ + t] = ix;
    }
}

// ================= MLP building blocks =================
// LDS pitches 65/129 (=1 mod 32): coalesced global staging reads AND
// conflict-free LDS writes/reads. GEMM k-loops are k-chunked with FULLY
// unrolled inner loops so x-chunk register arrays have static indices
// (dynamic indexing demotes arrays to scratch -> 3.3 GB spill traffic, R5 bug).

__device__ inline unsigned bfpack(float a, float b) {
    unsigned ua = __float_as_uint(a); ua = (ua + 0x7fffu + ((ua >> 16) & 1u)) >> 16;
    unsigned ub = __float_as_uint(b); ub = (ub + 0x7fffu + ((ub >> 16) & 1u)) >> 16;
    return ua | (ub << 16);
}
__device__ inline float bflo(unsigned u) { return __uint_as_float(u << 16); }
__device__ inline float bfhi(unsigned u) { return __uint_as_float(u & 0xffff0000u); }

template<int K>   // w: [64][K] row-major -> wT[k*65 + d]
__device__ inline void stage_w64(const float* __restrict__ w, float* wT, int t) {
    constexpr int tot = K * 64;
    for (int i = t; i < tot; i += 256) {
        int d = i / K, k = i - d * K;          // consecutive i -> coalesced global
        wT[k*65 + d] = w[i];
    }
}
// w2: [128][64] -> wT[k*129 + sidx], sidx = r*32+g*4+c for d = g*16+r*4+c
__device__ inline void stage_w128(const float* __restrict__ w, float* wT, int t) {
    for (int i = t; i < 8192; i += 256) {
        int d = i >> 6, k = i & 63;            // consecutive i -> coalesced global
        int sidx = ((d >> 2) & 3) * 32 + (d >> 4) * 4 + (d & 3);
        wT[k*129 + sidx] = w[i];
    }
}

template<int K>  // acc[j] <-> d = g*8+j, xs = row base (pitch 68)
__device__ inline void gemm64(const float* xs, const float* wT,
                              const float* __restrict__ bias, int g, float* acc) {
    float4 ba = *(const float4*)&bias[g*8], bb = *(const float4*)&bias[g*8+4];
    acc[0]=ba.x; acc[1]=ba.y; acc[2]=ba.z; acc[3]=ba.w;
    acc[4]=bb.x; acc[5]=bb.y; acc[6]=bb.z; acc[7]=bb.w;
    constexpr int NC = K / 16;
#pragma unroll
    for (int c = 0; c < NC; c++) {
        float xr[16];
#pragma unroll
        for (int i = 0; i < 4; i++) *(float4*)&xr[i*4] = *(const float4*)&xs[c*16 + i*4];
#pragma unroll
        for (int k2 = 0; k2 < 16; k2++) {
            int k = c*16 + k2;
            float4 wa = *(const float4*)&wT[k*65 + g*8];
            float4 wb = *(const float4*)&wT[k*65 + g*8 + 4];
            float x = xr[k2];
            acc[0] += x*wa.x; acc[1] += x*wa.y; acc[2] += x*wa.z; acc[3] += x*wa.w;
            acc[4] += x*wb.x; acc[5] += x*wb.y; acc[6] += x*wb.z; acc[7] += x*wb.w;
        }
    }
#pragma unroll
    for (int k = NC*16; k < K; k++) {          // remainder (K=67 -> 3 scalar reads)
        float x = xs[k];
        float4 wa = *(const float4*)&wT[k*65 + g*8];
        float4 wb = *(const float4*)&wT[k*65 + g*8 + 4];
        acc[0] += x*wa.x; acc[1] += x*wa.y; acc[2] += x*wa.z; acc[3] += x*wa.w;
        acc[4] += x*wb.x; acc[5] += x*wb.y; acc[6] += x*wb.z; acc[7] += x*wb.w;
    }
}

// acc[r*4+c] <-> d = g*16 + r*4 + c; x read from LDS row (pitch 68), K=64
__device__ inline void gemm128(const float* xs, const float* wT,
                               const float* __restrict__ bias, int g, float* acc) {
#pragma unroll
    for (int r = 0; r < 4; r++) {
        float4 bq = *(const float4*)&bias[g*16 + r*4];
        acc[r*4+0]=bq.x; acc[r*4+1]=bq.y; acc[r*4+2]=bq.z; acc[r*4+3]=bq.w;
    }
#pragma unroll
    for (int c = 0; c < 4; c++) {
        float xr[16];
#pragma unroll
        for (int i = 0; i < 4; i++) *(float4*)&xr[i*4] = *(const float4*)&xs[c*16 + i*4];
#pragma unroll
        for (int k2 = 0; k2 < 16; k2++) {
            int k = c*16 + k2;
            float x = xr[k2];
#pragma unroll
            for (int r = 0; r < 4; r++) {
                float4 w = *(const float4*)&wT[k*129 + r*32 + g*4];
                acc[r*4+0] += x*w.x; acc[r*4+1] += x*w.y; acc[r*4+2] += x*w.z; acc[r*4+3] += x*w.w;
            }
        }
    }
}

template<int ND>
__device__ inline void stats_reduce(float* acc, int t, float* red, float* part) {
    constexpr int D = ND*8;
    int g = t & 7;
    float sq[ND];
#pragma unroll
    for (int j = 0; j < ND; j++) sq[j] = acc[j]*acc[j];
#pragma unroll
    for (int m = 8; m <= 32; m <<= 1) {
#pragma unroll
        for (int j = 0; j < ND; j++) {
            acc[j] += __shfl_xor(acc[j], m, 64);
            sq[j]  += __shfl_xor(sq[j], m, 64);
        }
    }
    if (((t >> 3) & 7) == 0) {
#pragma unroll
        for (int j = 0; j < ND; j++) {
            atomicAdd(&red[g*ND + j], acc[j]);
            atomicAdd(&red[D + g*ND + j], sq[j]);
        }
    }
    __syncthreads();
    for (int i = t; i < 2*D; i += 256) atomicAdd(&part[i], red[i]);
}

// bn+relu into LDS row; optionally pack bf16 to global cache (y1 cache)
template<bool WC>
__device__ inline void bnrelu64(const float* acc, const float* __restrict__ ca,
                                const float* __restrict__ cc, int g, float* yrow,
                                unsigned short* ycg) {
    float v[8];
#pragma unroll
    for (int j = 0; j < 8; j++) {
        int d = g*8 + j;
        float x = acc[j]*ca[d] + cc[d];
        v[j] = x > 0.f ? x : 0.f;
    }
    *(float4*)&yrow[g*8]   = make_float4(v[0],v[1],v[2],v[3]);
    *(float4*)&yrow[g*8+4] = make_float4(v[4],v[5],v[6],v[7]);
    if (WC) {
        uint4 q;
        q.x = bfpack(v[0],v[1]); q.y = bfpack(v[2],v[3]);
        q.z = bfpack(v[4],v[5]); q.w = bfpack(v[6],v[7]);
        *(uint4*)(ycg + g*8) = q;
    }
}

__device__ inline void gather_x(const float* __restrict__ xyz, const float* __restrict__ feat,
                                int b, float cx, float cy, float cz,
                                const int* idxs, float* xs, int t) {
    const float* xb = xyz + (size_t)b * N_ * 3;
    for (int i = t; i < S_*C0IN; i += 256) {
        int s = i / C0IN, c = i - s*C0IN;
        int p = idxs[s];
        float v;
        if (c == 0)      v = xb[p*3+0] - cx;
        else if (c == 1) v = xb[p*3+1] - cy;
        else if (c == 2) v = xb[p*3+2] - cz;
        else             v = feat[((size_t)b*N_ + p)*IN_ + (c - 3)];
        xs[s*68 + c] = v;
    }
}

// ---------------- MLP chain ----------------
// MODE: 0..3. CACHE: mode2: 1=write y1-bf16, 2=write z2-bf16; mode3:
// 1=read y1-bf16 (skip L0/L1). 0 = pure recompute.
template<int MODE, int CACHE>
__global__ __launch_bounds__(256, 3) void mlp_kernel(
    const float* __restrict__ xyz, const float* __restrict__ feat,
    const int* __restrict__ fps_idx, const int* __restrict__ ball_idx,
    const float* __restrict__ w0, const float* __restrict__ b0,
    const float* __restrict__ w1, const float* __restrict__ b1,
    const float* __restrict__ w2, const float* __restrict__ b2,
    const float* __restrict__ coef, float* __restrict__ stats_part,
    unsigned short* __restrict__ zc, float* __restrict__ out_feat) {
    constexpr bool SKIP01 = (MODE == 3 && CACHE == 1);
    __shared__ float wT[(MODE >= 2) ? 8256 : 4355];
    __shared__ float xs[2176];
    __shared__ float y0s[(MODE >= 1 && !SKIP01) ? 2176 : 4];
    __shared__ float red[(MODE >= 2) ? 256 : 128];
    __shared__ int idxs[32];
    constexpr int REDN = (MODE >= 2) ? 256 : 128;
    int t = threadIdx.x, blk = blockIdx.x;
    int b = blk >> 10;
    int s = t >> 3, g = t & 7;
    int slice = blk & 63;
    if (t < REDN) red[t] = 0.f;

    if (SKIP01) {
        stage_w128(w2, wT, t);
        // decode y1-bf16 cache into xs rows (t covers 32 rows x 8 dword-pairs)
        {
            int rs = t >> 3, rg = t & 7;
            uint2 q = *(const uint2*)(zc + (size_t)blk*2048 + rs*64 + rg*8);
            xs[rs*68 + rg*8 + 0] = bflo(q.x); xs[rs*68 + rg*8 + 1] = bfhi(q.x);
            xs[rs*68 + rg*8 + 2] = bflo(q.y); xs[rs*68 + rg*8 + 3] = bfhi(q.y);
            uint2 q2 = *(const uint2*)(zc + (size_t)blk*2048 + rs*64 + rg*8 + 4);
            xs[rs*68 + rg*8 + 4] = bflo(q2.x); xs[rs*68 + rg*8 + 5] = bfhi(q2.x);
            xs[rs*68 + rg*8 + 6] = bflo(q2.y); xs[rs*68 + rg*8 + 7] = bfhi(q2.y);
        }
        __syncthreads();
    } else {
        if (t < 32) idxs[t] = ball_idx[(size_t)blk*32 + t];
        __syncthreads();
        const float* xb = xyz + (size_t)b * N_ * 3;
        int cidx = fps_idx[blk];
        float cx = xb[cidx*3+0], cy = xb[cidx*3+1], cz = xb[cidx*3+2];
        gather_x(xyz, feat, b, cx, cy, cz, idxs, xs, t);
        stage_w64<67>(w0, wT, t);
        __syncthreads();
    }

    if (!SKIP01) {
        float acc[8];
        gemm64<67>(xs + s*68, wT, b0, g, acc);
        if (MODE == 0) { stats_reduce<8>(acc, t, red, stats_part + slice*512); return; }
        bnrelu64<false>(acc, coef, coef + 64, g, y0s + s*68, nullptr);
        __syncthreads();
        stage_w64<64>(w1, wT, t);
        __syncthreads();
        gemm64<64>(y0s + s*68, wT, b1, g, acc);
        if (MODE == 1) { stats_reduce<8>(acc, t, red, stats_part + slice*512 + 128); return; }
        __syncthreads();                                  // xs reads done; reuse as y1
        bnrelu64<(MODE == 2 && CACHE == 1)>(acc, coef + 128, coef + 192, g, xs + s*68,
                                            zc + (size_t)blk*2048 + s*64);
        stage_w128(w2, wT, t);
        __syncthreads();
    }

    float acc2[16];
    gemm128(xs + s*68, wT, b2, g, acc2);
    if (MODE == 2 && CACHE == 2) {
        unsigned short* zw = zc + (size_t)blk*4096 + s*128 + g*16;
        uint4 qa, qb;
        qa.x = bfpack(acc2[0],acc2[1]);   qa.y = bfpack(acc2[2],acc2[3]);
        qa.z = bfpack(acc2[4],acc2[5]);   qa.w = bfpack(acc2[6],acc2[7]);
        qb.x = bfpack(acc2[8],acc2[9]);   qb.y = bfpack(acc2[10],acc2[11]);
        qb.z = bfpack(acc2[12],acc2[13]); qb.w = bfpack(acc2[14],acc2[15]);
        *(uint4*)zw = qa; *(uint4*)(zw + 8) = qb;
    }
    if (MODE == 2) { stats_reduce<16>(acc2, t, red, stats_part + slice*512 + 256); return; }
    // final: bn+relu+max over s
    const float* ca = coef + 256; const float* cc = coef + 384;
    int* redI = (int*)red;
#pragma unroll
    for (int j = 0; j < 16; j++) {
        int d = g*16 + j;
        float x = acc2[j]*ca[d] + cc[d];
        x = x > 0.f ? x : 0.f;
#pragma unroll
        for (int m = 8; m <= 32; m <<= 1) {
            float o = __shfl_xor(x, m, 64);
            x = o > x ? o : x;
        }
        acc2[j] = x;
    }
    if (((t >> 3) & 7) == 0) {
#pragma unroll
        for (int j = 0; j < 16; j++) atomicMax(&redI[g*16+j], __float_as_int(acc2[j]));
    }
    __syncthreads();
    if (t < 128) out_feat[(size_t)blk*128 + t] = __int_as_float(redI[t]);
}

// gate-A finisher: read z2-bf16, bn+relu+max
__global__ __launch_bounds__(256) void f3_kernel(const unsigned short* __restrict__ zc,
                                                 const float* __restrict__ coef,
                                                 float* __restrict__ out_feat) {
    __shared__ int red[128];
    int t = threadIdx.x, blk = blockIdx.x;
    int g = t & 7;
    if (t < 128) red[t] = 0;   // outputs are post-ReLU >= 0
    __syncthreads();
    const uint4* zr = (const uint4*)(zc + (size_t)blk*4096 + t*16);
    uint4 q0 = zr[0], q1 = zr[1];
    float v[16];
    v[0]=bflo(q0.x); v[1]=bfhi(q0.x); v[2]=bflo(q0.y); v[3]=bfhi(q0.y);
    v[4]=bflo(q0.z); v[5]=bfhi(q0.z); v[6]=bflo(q0.w); v[7]=bfhi(q0.w);
    v[8]=bflo(q1.x); v[9]=bfhi(q1.x); v[10]=bflo(q1.y); v[11]=bfhi(q1.y);
    v[12]=bflo(q1.z); v[13]=bfhi(q1.z); v[14]=bflo(q1.w); v[15]=bfhi(q1.w);
    const float* ca = coef; const float* cc = coef + 128;
#pragma unroll
    for (int j = 0; j < 16; j++) {
        int d = g*16 + j;
        float x = v[j]*ca[d] + cc[d];
        x = x > 0.f ? x : 0.f;
#pragma unroll
        for (int m = 8; m <= 32; m <<= 1) {
            float o = __shfl_xor(x, m, 64);
            x = o > x ? o : x;
        }
        if (((t >> 3) & 7) == 0) atomicMax(&red[d], __float_as_int(x));
    }
    __syncthreads();
    if (t < 128) out_feat[(size_t)blk*128 + t] = __int_as_float(red[t]);
}

__global__ void finalize_kernel(const float* __restrict__ part,
                                const float* __restrict__ gamma,
                                const float* __restrict__ beta,
                                float* __restrict__ coef, int C) {
    int t = threadIdx.x;
    if (t < C) {
        float sum = 0.f, sq = 0.f;
        for (int sl = 0; sl < 64; sl++) {
            sum += part[sl*512 + t];
            sq  += part[sl*512 + C + t];
        }
        float inv_n = 1.0f / (float)NTOT;
        float mean = sum * inv_n;
        float var = sq * inv_n - mean * mean;
        float rstd = 1.0f / sqrtf(var + 1e-5f);
        float a = gamma[t] * rstd;
        coef[t] = a;
        coef[C + t] = beta[t] - mean * a;
    }
}

extern "C" void kernel_launch(void* const* d_in, const int* in_sizes, int n_in,
                              void* d_out, int out_size, void* d_ws, size_t ws_size,
                              hipStream_t stream) {
    const float* xyz  = (const float*)d_in[0];
    const float* feat = (const float*)d_in[1];
    const float* w0 = (const float*)d_in[2];  const float* b0 = (const float*)d_in[3];
    const float* g0 = (const float*)d_in[4];  const float* be0 = (const float*)d_in[5];
    const float* w1 = (const float*)d_in[6];  const float* b1 = (const float*)d_in[7];
    const float* g1 = (const float*)d_in[8];  const float* be1 = (const float*)d_in[9];
    const float* w2 = (const float*)d_in[10]; const float* b2 = (const float*)d_in[11];
    const float* g2 = (const float*)d_in[12]; const float* be2 = (const float*)d_in[13];
    float* out_xyz  = (float*)d_out;
    float* out_feat = out_xyz + B_*M_*3;

    char* ws = (char*)d_ws;
    int* fps_i  = (int*)ws;                                  // 65536 B
    int* ball_i = (int*)(ws + 65536);                        // 2097152 B
    float* stats_part = (float*)(ws + 65536 + 2097152);      // 131072 B
    float* coef = (float*)(ws + 65536 + 2097152 + 131072);   // 2048 B
    unsigned short* zc = (unsigned short*)(ws + ((size_t)4 << 20));
    bool gateA = ws_size >= ((size_t)4 << 20) + 134217728ull + (1u << 20);  // z2-bf16
    bool gateB = !gateA && ws_size >= ((size_t)4 << 20) + 67108864ull + (1u << 20); // y1-bf16

    hipMemsetAsync(stats_part, 0, 131072, stream);
    fps_kernel<<<B_, 512, 0, stream>>>(xyz, fps_i, out_xyz);
    ballq_kernel<<<B_*M_, 256, 0, stream>>>(xyz, fps_i, ball_i);
    mlp_kernel<0,0><<<B_*M_, 256, 0, stream>>>(xyz, feat, fps_i, ball_i,
        w0, b0, w1, b1, w2, b2, coef, stats_part, zc, out_feat);
    finalize_kernel<<<1, 64, 0, stream>>>(stats_part, g0, be0, coef, 64);
    mlp_kernel<1,0><<<B_*M_, 256, 0, stream>>>(xyz, feat, fps_i, ball_i,
        w0, b0, w1, b1, w2, b2, coef, stats_part, zc, out_feat);
    finalize_kernel<<<1, 64, 0, stream>>>(stats_part + 128, g1, be1, coef + 128, 64);
    if (gateA)
        mlp_kernel<2,2><<<B_*M_, 256, 0, stream>>>(xyz, feat, fps_i, ball_i,
            w0, b0, w1, b1, w2, b2, coef, stats_part, zc, out_feat);
    else if (gateB)
        mlp_kernel<2,1><<<B_*M_, 256, 0, stream>>>(xyz, feat, fps_i, ball_i,
            w0, b0, w1, b1, w2, b2, coef, stats_part, zc, out_feat);
    else
        mlp_kernel<2,0><<<B_*M_, 256, 0, stream>>>(xyz, feat, fps_i, ball_i,
            w0, b0, w1, b1, w2, b2, coef, stats_part, zc, out_feat);
    finalize_kernel<<<1, 128, 0, stream>>>(stats_part + 256, g2, be2, coef + 256, 128);
    if (gateA)
        f3_kernel<<<B_*M_, 256, 0, stream>>>(zc, coef + 256, out_feat);
    else if (gateB)
        mlp_kernel<3,1><<<B_*M_, 256, 0, stream>>>(xyz, feat, fps_i, ball_i,
            w0, b0, w1, b1, w2, b2, coef, stats_part, zc, out_feat);
    else
        mlp_kernel<3,0><<<B_*M_, 256, 0, stream>>>(xyz, feat, fps_i, ball_i,
            w0, b0, w1, b1, w2, b2, coef, stats_part, zc, out_feat);
}